// Round 8
// baseline (170.299 us; speedup 1.0000x reference)
//
#include <hip/hip_runtime.h>

// VQ-VAE VectorQuantizer: fp16 single-term MFMA distance + codebook-stationary
// exact fp32 slice re-rank. z: (32,64,64,64) NCHW fp32; codebook: (1024,64).
// d_out: [0]=loss, [1..]=z_q (NCHW).
//
// R16 (from R15 post-mortem): 3-term main (+30us) vs cheap fix (-37us) was a
// wash; every main variant is stall-dominated (pipes <45%) with issue work
// ~7-10us -- main's floor in this structure is the R12 61us kernel. Keep it
// VERBATIM (1-term fp16, TAU=0.02, n~12-16K flags) and fix the FIX instead:
//  - vq_fix1: codebook-stationary. 512 blocks = 64 flag-groups x 8 slices.
//    Each block: 128-code fp32 slice in LDS (row stride 65 -> only 2-way
//    bank alias, free). Per flag: wave stages z row (64 ch) to LDS, each
//    lane scores codes (slice*128+lane, +64+lane) exactly in fp32, u64
//    shuffle-min, ONE atomicMin(key = dist_bits<<32 | idx) -> exact argmin
//    with smallest-index tie-break across slices.
//  - vq_fix2: grid-stride over flags; where exact idx != main's idx, rewrite
//    the z_q row + atomicAdd loss_adj (d_exact - (m1 + ||z||^2)); then the
//    R12-proven done_cnt/threadfence finalize sums loss_part[1024]+loss_adj.
//  - per-flag cost: ~256KB L2 codebook scan (R12 fix) -> ~1.6K cyc LDS+VALU.
// vq_prep: R12's + exact_key[FCAP] init to ~0.

#define CB_N   1024
#define KDIM   64
#define HWD    4096
#define CHW    (KDIM * HWD)
#define NQ     131072
#define TOTALF 8388608.0f
#define TAU    0.02f
#define FCAP   16384
#define CHUNK  128            // codes per LDS chunk
#define NCHUNK (CB_N / CHUNK)

typedef __attribute__((ext_vector_type(8))) _Float16 half8;
typedef __attribute__((ext_vector_type(4))) float    f32x4;

// async 16B/lane global->LDS copy (wave-uniform contiguous; m97 pattern)
__device__ __forceinline__ void gload_lds16(const void* g, void* l) {
    __builtin_amdgcn_global_load_lds(
        (const __attribute__((address_space(1))) unsigned int*)g,
        (__attribute__((address_space(3))) unsigned int*)l,
        16, 0, 0);
}

// ---------- ws layout (byte offsets) ----------
// 0: loss_adj  4: flag_cnt  8: done_cnt
// 128:    loss_part f32[1024]
// 4224:   norms     f32[1024]
// 8320:   cbh_sw    u16[1024*64]   (fp16, rotate-swizzled row segments)
// 266368: flag_q i32[FCAP]  331904: flag_m1 f32[FCAP]  397440: flag_idx i32[FCAP]
// 462976: exact_key u64[FCAP]

// ---------------- prep: fp16 convert, swizzled rows, norms, counters --------
__global__ void vq_prep(const float* __restrict__ cb,
                        float* __restrict__ norms,
                        unsigned short* __restrict__ cbh,
                        float* __restrict__ loss_adj,
                        int* __restrict__ flag_cnt,
                        int* __restrict__ done_cnt,
                        unsigned long long* __restrict__ exact_key) {
    const int tid = blockIdx.x * 256 + threadIdx.x;
    if (tid == 0) *loss_adj = 0.0f;
    if (tid == 1) *flag_cnt = 0;
    if (tid == 2) *done_cnt = 0;
    // init exact keys to +inf-like (4096 threads x 4)
    for (int i = tid; i < FCAP; i += 4096) exact_key[i] = ~0ull;

    const int j  = tid >> 2;
    const int s2 = tid & 3;

    const float4* r4 = (const float4*)(cb + (size_t)j * KDIM);
    float s_norm = 0.0f;
    #pragma unroll
    for (int seg8 = 0; seg8 < 2; ++seg8) {
        const int s = s2 * 2 + seg8;
        float4 v0 = r4[s * 2 + 0];
        float4 v1 = r4[s * 2 + 1];
        float e[8] = {v0.x, v0.y, v0.z, v0.w, v1.x, v1.y, v1.z, v1.w};
        unsigned hh[4];
        #pragma unroll
        for (int c = 0; c < 8; ++c) {
            float x = e[c];
            s_norm = fmaf(x, x, s_norm);
            union { _Float16 h; unsigned short u; } cv;
            cv.h = (_Float16)x;                       // RNE fp16
            if ((c & 1) == 0) hh[c >> 1] = cv.u;
            else              hh[c >> 1] |= ((unsigned)cv.u) << 16;
        }
        const int p = (s + j) & 7;                    // bank-deconflict rotate
        *(uint4*)(cbh + (size_t)j * KDIM + p * 8) = make_uint4(hh[0], hh[1], hh[2], hh[3]);
    }
    s_norm += __shfl_xor(s_norm, 1, 64);
    s_norm += __shfl_xor(s_norm, 2, 64);
    if (s2 == 0) norms[j] = s_norm;
}

// ---------------- main (R12 verbatim: 61us proven) --------------------------
__global__ __launch_bounds__(256, 3) void vq_main(
        const float* __restrict__ z,
        const float* __restrict__ cb,
        const unsigned short* __restrict__ cbh,
        const float* __restrict__ norms,
        float* __restrict__ out,
        float* __restrict__ loss_part,
        int* __restrict__ flag_q,
        float* __restrict__ flag_m1,
        int* __restrict__ flag_idx,
        int* __restrict__ flag_cnt) {
    __shared__ float          norms_s[CB_N];             // 4 KB
    __shared__ unsigned short bh_s[2][CHUNK * KDIM];     // 2 x 16 KB (dbuf)
    __shared__ float          zn_s[128];
    __shared__ int            idx_s[128];
    __shared__ float          wsum_s[4];

    const int tid  = threadIdx.x;
    const int w    = tid >> 6;
    const int lane = tid & 63;
    const int quad = lane >> 4;
    const int l16  = lane & 15;
    const int qb   = blockIdx.x * 128;     // block's 128 queries (same batch b)
    const int b    = qb >> 12;
    const int hw0  = qb & 4095;
    const int ch0  = blockIdx.x & (NCHUNK - 1);   // de-phase chunk start

    // ---- issue stage of chunk 0 FIRST (flies under the z-read prologue)
    {
        const char* gh = (const char*)cbh + (size_t)(ch0 & (NCHUNK - 1)) * (CHUNK * KDIM * 2);
        char* lh = (char*)(&bh_s[0][0]);
        #pragma unroll
        for (int i = 0; i < 4; ++i) {
            const int off = (w * 4 + i) * 1024 + lane * 16;
            gload_lds16(gh + off, lh + off);
        }
    }

    // ---- stage all code norms into LDS
    *(float4*)(norms_s + tid * 4) = *(const float4*)(norms + tid * 4);

    // ---- stage A-frags: wave w owns queries [32w, 32w+32); 2 tiles of 16.
    const float* zbase = z + (size_t)b * CHW + hw0 + 32 * w;
    half8 ah[2][2];
    float znp[2] = {0.f, 0.f};
    #pragma unroll
    for (int t = 0; t < 2; ++t)
        #pragma unroll
        for (int ks = 0; ks < 2; ++ks)
            #pragma unroll
            for (int j = 0; j < 8; ++j) {
                float v = zbase[(size_t)(ks * 32 + quad * 8 + j) * HWD + t * 16 + l16];
                znp[t] = fmaf(v, v, znp[t]);
                ah[t][ks][j] = (_Float16)(-2.0f * v);   // RNE fp16
            }
    #pragma unroll
    for (int t = 0; t < 2; ++t) {
        znp[t] += __shfl_xor(znp[t], 16, 64);
        znp[t] += __shfl_xor(znp[t], 32, 64);
    }
    if (lane < 16) {
        zn_s[32 * w + lane]      = znp[0];
        zn_s[32 * w + 16 + lane] = znp[1];
    }

    float m1[2][4], m2[2][4];
    int   i1[2][4];
    #pragma unroll
    for (int t = 0; t < 2; ++t)
        #pragma unroll
        for (int r = 0; r < 4; ++r) { m1[t][r] = 3.4e38f; m2[t][r] = 3.4e38f; i1[t][r] = 0; }

    // loop-invariant swizzled segment offsets (ks=0 / ks=1)
    const int p0 = ((quad + l16) & 7) * 8;
    const int p1 = ((4 + quad + l16) & 7) * 8;

    f32x4 bank[2][2];               // [tile-parity][t] -- deferred tracking
    bank[0][0] = bank[0][1] = (f32x4){0.f, 0.f, 0.f, 0.f};
    bank[1][0] = bank[1][1] = (f32x4){0.f, 0.f, 0.f, 0.f};
    int prevCode = 0;

    __syncthreads();                // chunk 0 staged + norms_s/zn_s visible
    int cur = 0;

    for (int cc = 0; cc < NCHUNK; ++cc) {
        // ---- issue next chunk's stage into the OTHER buffer (overlaps compute)
        if (cc + 1 < NCHUNK) {
            const int chn = (cc + 1 + ch0) & (NCHUNK - 1);
            const char* gh = (const char*)cbh + (size_t)chn * (CHUNK * KDIM * 2);
            char* lh = (char*)(&bh_s[cur ^ 1][0]);
            #pragma unroll
            for (int i = 0; i < 4; ++i) {
                const int off = (w * 4 + i) * 1024 + lane * 16;
                gload_lds16(gh + off, lh + off);
            }
        }

        const int ch = (cc + ch0) & (NCHUNK - 1);
        #pragma unroll
        for (int t8 = 0; t8 < 8; ++t8) {
            const int crow = t8 * 16 + l16;            // chunk-local code row
            const float nv = norms_s[ch * CHUNK + crow];
            const half8 bh0 = *(const half8*)(&bh_s[cur][crow * KDIM + p0]);
            const half8 bh1 = *(const half8*)(&bh_s[cur][crow * KDIM + p1]);
            const int code = ch * CHUNK + crow;
            const int bk = t8 & 1, pv = bk ^ 1;

            // track the DEFERRED tile (previous t8) held in bank[pv];
            // independent of bank[bk]'s MFMAs below -> overlaps them
            if (cc + t8 > 0) {
                #pragma unroll
                for (int t = 0; t < 2; ++t)
                    #pragma unroll
                    for (int r = 0; r < 4; ++r) {
                        float d = bank[pv][t][r];
                        bool cnd = d < m1[t][r];
                        m2[t][r] = __builtin_amdgcn_fmed3f(d, m1[t][r], m2[t][r]);
                        m1[t][r] = fminf(m1[t][r], d);
                        i1[t][r] = cnd ? prevCode : i1[t][r];
                    }
            }

            #pragma unroll
            for (int t = 0; t < 2; ++t) {
                f32x4 acc = {nv, nv, nv, nv};
                acc = __builtin_amdgcn_mfma_f32_16x16x32_f16(ah[t][0], bh0, acc, 0, 0, 0);
                acc = __builtin_amdgcn_mfma_f32_16x16x32_f16(ah[t][1], bh1, acc, 0, 0, 0);
                bank[bk][t] = acc;
            }
            prevCode = code;
        }

        __syncthreads();   // implicit vmcnt(0): next buffer landed; cur reads done
        cur ^= 1;
    }
    // final deferred tile (last t8=7 wrote bank[1])
    {
        #pragma unroll
        for (int t = 0; t < 2; ++t)
            #pragma unroll
            for (int r = 0; r < 4; ++r) {
                float d = bank[1][t][r];
                bool cnd = d < m1[t][r];
                m2[t][r] = __builtin_amdgcn_fmed3f(d, m1[t][r], m2[t][r]);
                m1[t][r] = fminf(m1[t][r], d);
                i1[t][r] = cnd ? prevCode : i1[t][r];
            }
    }

    // ---- merge across 16 lanes (code residues), first-index ties
    #pragma unroll
    for (int s = 1; s < 16; s <<= 1)
        #pragma unroll
        for (int t = 0; t < 2; ++t)
            #pragma unroll
            for (int r = 0; r < 4; ++r) {
                float o1 = __shfl_xor(m1[t][r], s, 64);
                int   oi = __shfl_xor(i1[t][r], s, 64);
                float o2 = __shfl_xor(m2[t][r], s, 64);
                m2[t][r] = __builtin_amdgcn_fmed3f(m1[t][r], o1, fminf(m2[t][r], o2));
                if (o1 < m1[t][r] || (o1 == m1[t][r] && oi < i1[t][r])) {
                    m1[t][r] = o1; i1[t][r] = oi;
                }
            }

    // ---- owners (l16==0): publish idx, batched flags, loss partial
    float lsum = 0.0f;
    if (l16 == 0) {
        int nf = 0;
        #pragma unroll
        for (int t = 0; t < 2; ++t)
            #pragma unroll
            for (int r = 0; r < 4; ++r) {
                const int ql = 32 * w + t * 16 + quad * 4 + r;
                idx_s[ql] = i1[t][r];
                lsum += m1[t][r] + zn_s[ql];
                nf += (m2[t][r] - m1[t][r] < TAU) ? 1 : 0;
            }
        if (nf) {                      // ONE atomic per flagging owner thread
            int pos = atomicAdd(flag_cnt, nf);
            #pragma unroll
            for (int t = 0; t < 2; ++t)
                #pragma unroll
                for (int r = 0; r < 4; ++r)
                    if (m2[t][r] - m1[t][r] < TAU) {
                        if (pos < FCAP) {
                            flag_q[pos]   = qb + 32 * w + t * 16 + quad * 4 + r;
                            flag_m1[pos]  = m1[t][r];
                            flag_idx[pos] = i1[t][r];
                        }
                        ++pos;
                    }
        }
    }
    #pragma unroll
    for (int s = 1; s < 64; s <<= 1) lsum += __shfl_xor(lsum, s, 64);
    if (lane == 0) wsum_s[w] = lsum;
    __syncthreads();                   // idx_s + wsum_s visible

    // per-block loss partial: plain store, NO global atomic
    if (tid == 0)
        loss_part[blockIdx.x] = wsum_s[0] + wsum_s[1] + wsum_s[2] + wsum_s[3];

    // ---- epilogue: thread -> (query tid&127, channels [32*(tid>>7),+32))
    {
        const int q   = tid & 127;
        const int cs  = (tid >> 7) * 32;
        const int idx = idx_s[q];
        const float4* row = (const float4*)(cb + (size_t)idx * KDIM + cs);
        float* op = out + 1 + (size_t)b * CHW + (size_t)cs * HWD + hw0 + q;
        #pragma unroll
        for (int i4 = 0; i4 < 8; ++i4) {
            float4 v = row[i4];
            op[(size_t)(i4 * 4 + 0) * HWD] = v.x;
            op[(size_t)(i4 * 4 + 1) * HWD] = v.y;
            op[(size_t)(i4 * 4 + 2) * HWD] = v.z;
            op[(size_t)(i4 * 4 + 3) * HWD] = v.w;
        }
    }
}

// ---------------- fix1: codebook-stationary exact slice scoring -------------
// 512 blocks = 64 flag-groups x 8 slices. Block holds slice (128 codes, fp32)
// in LDS with row stride 65 (2-way bank alias only). Wave per flag: stage z
// row to LDS, lane scores codes slice*128+lane and +64+lane, u64 shuffle-min,
// one atomicMin(dist_bits<<32 | idx) -> exact global argmin, min-idx ties.
__global__ __launch_bounds__(256, 4) void vq_fix1(
                       const float* __restrict__ z,
                       const float* __restrict__ cb,
                       const int* __restrict__ flag_q,
                       const int* __restrict__ flag_cnt,
                       unsigned long long* __restrict__ exact_key) {
    __shared__ float cbs[128 * 65];     // 33.3 KB padded slice
    __shared__ float zf[4][64];

    const int tid   = threadIdx.x;
    const int w     = tid >> 6;
    const int lane  = tid & 63;
    const int slice = blockIdx.x & 7;
    const int grp   = blockIdx.x >> 3;  // 0..63

    // stage slice fp32 -> LDS (coalesced: i*256+tid float4 indexing)
    {
        const float4* src = (const float4*)(cb + (size_t)slice * 128 * KDIM);
        #pragma unroll
        for (int i = 0; i < 8; ++i) {
            const int idx = i * 256 + tid;        // 0..2047 float4s
            float4 v = src[idx];
            const int row = idx >> 4, c4 = (idx & 15) * 4;
            float* dst = cbs + row * 65 + c4;
            dst[0] = v.x; dst[1] = v.y; dst[2] = v.z; dst[3] = v.w;
        }
    }
    __syncthreads();

    int n = *flag_cnt;
    if (n > FCAP) n = FCAP;

    const int j0 = slice * 128 + lane;
    const float* r0 = cbs + lane * 65;
    const float* r1 = cbs + (lane + 64) * 65;

    for (int f = grp * 4 + w; f < n; f += 256) {
        const int q  = flag_q[f];
        const int b  = q >> 12;
        const int hw = q & 4095;

        zf[w][lane] = z[(size_t)b * CHW + (size_t)lane * HWD + hw];
        // same-wave LDS RAW: compiler inserts lgkmcnt wait before reads

        float d0 = 0.f, d1 = 0.f;
        #pragma unroll
        for (int c = 0; c < 64; ++c) {
            const float zc = zf[w][c];             // broadcast (conflict-free)
            float a0 = zc - r0[c]; d0 = fmaf(a0, a0, d0);
            float a1 = zc - r1[c]; d1 = fmaf(a1, a1, d1);
        }
        unsigned long long k0 = (((unsigned long long)__float_as_uint(d0)) << 32) | (unsigned)j0;
        unsigned long long k1 = (((unsigned long long)__float_as_uint(d1)) << 32) | (unsigned)(j0 + 64);
        unsigned long long k = k0 < k1 ? k0 : k1;
        #pragma unroll
        for (int s = 1; s < 64; s <<= 1) {
            unsigned long long o = __shfl_xor(k, s, 64);
            k = o < k ? o : k;
        }
        if (lane == 0) atomicMin(&exact_key[f], k);
    }
}

// ---------------- fix2: patch changed rows, adjust + finalize loss ----------
__global__ __launch_bounds__(256, 4) void vq_fix2(
                       const float* __restrict__ z,
                       const float* __restrict__ cb,
                       float* __restrict__ out,
                       float* __restrict__ loss_adj,
                       const float* __restrict__ loss_part,
                       const int* __restrict__ flag_q,
                       const float* __restrict__ flag_m1,
                       const int* __restrict__ flag_idx,
                       const int* __restrict__ flag_cnt,
                       const unsigned long long* __restrict__ exact_key,
                       int* __restrict__ done_cnt) {
    __shared__ float red_s[4];
    __shared__ int   last_s;

    const int w    = threadIdx.x >> 6;
    const int lane = threadIdx.x & 63;
    const int gw   = blockIdx.x * 4 + w;
    const int NW   = gridDim.x * 4;      // 1024 waves

    int n = *flag_cnt;
    if (n > FCAP) n = FCAP;

    for (int f = gw; f < n; f += NW) {
        const unsigned long long k = exact_key[f];
        const int jex = (int)(unsigned)(k & 0xFFFFFFFFu);
        const int io  = flag_idx[f];
        if (jex != io) {                 // wave-uniform branch
            const float dex = __uint_as_float((unsigned)(k >> 32));
            const int q  = flag_q[f];
            const int b  = q >> 12;
            const int hw = q & 4095;
            // recompute ||z||^2 (lane l holds channel l)
            float zv = z[(size_t)b * CHW + (size_t)lane * HWD + hw];
            float zn = zv * zv;
            #pragma unroll
            for (int s = 1; s < 64; s <<= 1) zn += __shfl_xor(zn, s, 64);
            // rewrite z_q row with exact winner
            out[1 + (size_t)b * CHW + (size_t)lane * HWD + hw] = cb[(size_t)jex * KDIM + lane];
            if (lane == 0) atomicAdd(loss_adj, dex - (flag_m1[f] + zn));
        }
    }

    __syncthreads();
    if (threadIdx.x == 0) {
        __threadfence();
        last_s = (atomicAdd(done_cnt, 1) == (int)gridDim.x - 1) ? 1 : 0;
    }
    __syncthreads();

    if (last_s) {
        float s = 0.0f;
        for (int i = threadIdx.x; i < 1024; i += 256) s += loss_part[i];
        #pragma unroll
        for (int sh = 1; sh < 64; sh <<= 1) s += __shfl_xor(s, sh, 64);
        if (lane == 0) red_s[w] = s;
        __syncthreads();
        if (threadIdx.x == 0) {
            float L = red_s[0] + red_s[1] + red_s[2] + red_s[3]
                    + atomicAdd(loss_adj, 0.0f);
            out[0] = 1.25f * L / TOTALF;
        }
    }
}

extern "C" void kernel_launch(void* const* d_in, const int* in_sizes, int n_in,
                              void* d_out, int out_size, void* d_ws, size_t ws_size,
                              hipStream_t stream) {
    const float* z  = (const float*)d_in[0];
    const float* cb = (const float*)d_in[1];
    float* out      = (float*)d_out;
    char*  ws       = (char*)d_ws;

    float*              loss_adj  = (float*)(ws + 0);
    int*                flag_cnt  = (int*)(ws + 4);
    int*                done_cnt  = (int*)(ws + 8);
    float*              loss_part = (float*)(ws + 128);
    float*              norms     = (float*)(ws + 4224);
    unsigned short*     cbh       = (unsigned short*)(ws + 8320);
    int*                flag_q    = (int*)(ws + 266368);
    float*              flag_m1   = (float*)(ws + 331904);
    int*                flag_idx  = (int*)(ws + 397440);
    unsigned long long* exact_key = (unsigned long long*)(ws + 462976);

    vq_prep<<<dim3(16), dim3(256), 0, stream>>>(cb, norms, cbh,
                                                loss_adj, flag_cnt, done_cnt,
                                                exact_key);

    vq_main<<<dim3(NQ / 128), dim3(256), 0, stream>>>(z, cb, cbh, norms, out,
                                                      loss_part, flag_q, flag_m1,
                                                      flag_idx, flag_cnt);

    vq_fix1<<<dim3(512), dim3(256), 0, stream>>>(z, cb, flag_q, flag_cnt,
                                                 exact_key);

    vq_fix2<<<dim3(256), dim3(256), 0, stream>>>(z, cb, out, loss_adj, loss_part,
                                                 flag_q, flag_m1, flag_idx,
                                                 flag_cnt, exact_key, done_cnt);
}